// Round 4
// baseline (275.160 us; speedup 1.0000x reference)
//
#include <hip/hip_runtime.h>
#include <stdint.h>
#include <stddef.h>

typedef __bf16 bf16;
typedef uint32_t u32;
typedef __attribute__((ext_vector_type(8))) __bf16 bf16x8;
typedef __attribute__((ext_vector_type(4))) __bf16 bf16x4;
typedef __attribute__((ext_vector_type(4))) float f32x4;
typedef __attribute__((ext_vector_type(16))) float f32x16;
typedef __attribute__((ext_vector_type(8))) unsigned short u16x8;
typedef __attribute__((ext_vector_type(4))) u32 u32x4;

// -------- async global->LDS (16B) --------
__device__ __forceinline__ void gload_lds16(const void* g, void* l) {
  __builtin_amdgcn_global_load_lds(
      (const __attribute__((address_space(1))) unsigned int*)g,
      (__attribute__((address_space(3))) unsigned int*)l, 16, 0, 0);
}

__device__ __forceinline__ float fast_exp2(float x) {
#if __has_builtin(__builtin_amdgcn_exp2f)
  return __builtin_amdgcn_exp2f(x);
#else
  float r; asm("v_exp_f32 %0, %1" : "=v"(r) : "v"(x)); return r;
#endif
}

__device__ __forceinline__ u32 cvtpk_bf16(float lo, float hi_) {
  u32 r;
  asm("v_cvt_pk_bf16_f32 %0, %1, %2" : "=v"(r) : "v"(lo), "v"(hi_));
  return r;
}

// swap: a[32:63] <-> b[0:31]  (ONLY safe with distinct-origin a,b values)
__device__ __forceinline__ void pl32swap(u32& a, u32& b) {
  asm("v_permlane32_swap_b32 %0, %1" : "+v"(a), "+&v"(b));
}

// cross-half (lane ^ 32) reduce — via DS shuffle (bulletproof)
__device__ __forceinline__ float xhalf_max(float v) {
  return fmaxf(v, __shfl_xor(v, 32, 64));
}
__device__ __forceinline__ float xhalf_sum(float v) {
  return v + __shfl_xor(v, 32, 64);
}

// ================= convert x: fp32 -> bf16 =================
__global__ void cvt_bf16_kernel(const float* __restrict__ in, bf16* __restrict__ out, int n) {
  int i = (blockIdx.x * blockDim.x + threadIdx.x) * 4;
  if (i < n) {
    float4 v = *(const float4*)(in + i);
    bf16x4 o;
    o[0] = (bf16)v.x; o[1] = (bf16)v.y; o[2] = (bf16)v.z; o[3] = (bf16)v.w;
    *(bf16x4*)(out + i) = o;
  }
}

// ======= transpose+convert: in[K_][N_] fp32 -> out[N_][K_] bf16 =======
__global__ void transpose_cvt_kernel(const float* __restrict__ in, bf16* __restrict__ out,
                                     int K_, int N_) {
  __shared__ __align__(16) bf16 t[64][65];
  const int nb = blockIdx.x * 64, kb = blockIdx.y * 64;
  const int c = threadIdx.x & 63, r0 = (threadIdx.x >> 6) * 16;
#pragma unroll
  for (int i = 0; i < 16; ++i) {
    int rr = r0 + i;
    t[c][rr] = (bf16)in[(size_t)(kb + rr) * N_ + nb + c];
  }
  __syncthreads();
#pragma unroll
  for (int i = 0; i < 16; ++i) {
    int rr = r0 + i;
    out[(size_t)(nb + rr) * K_ + kb + c] = t[rr][c];
  }
}

// ================= GEMM: C[M,N] = A[M,K] * BT[N,K]^T + bias =================
#define BM 128
#define BN 128
#define BK 64

template <int MODE>
__global__ __launch_bounds__(256) void gemm_bt(
    const bf16* __restrict__ A, const bf16* __restrict__ BT,
    const float* __restrict__ bias, void* __restrict__ Cout,
    int M, int N, int K, float qscale, int qcols) {
  __shared__ __align__(16) bf16 As[BM * BK];
  __shared__ __align__(16) bf16 Bs[BN * BK];
  const int tid = threadIdx.x;
  const int lane = tid & 63;
  const int w = tid >> 6;
  const int wm = (w >> 1) * 64;
  const int wn = (w & 1) * 64;
  const int m0 = blockIdx.x * BM;
  const int n0 = blockIdx.y * BN;
  const int r = lane & 15, g = lane >> 4;

  f32x4 acc[4][4] = {};

  for (int k0 = 0; k0 < K; k0 += BK) {
    __syncthreads();
#pragma unroll
    for (int i = 0; i < 4; ++i) {
      int id = tid + i * 256;
      int row = id >> 3, c = id & 7;
      int sc = c ^ (row & 7);
      gload_lds16(A + (size_t)(m0 + row) * K + k0 + sc * 8, As + id * 8);
      gload_lds16(BT + (size_t)(n0 + row) * K + k0 + sc * 8, Bs + id * 8);
    }
    __syncthreads();
#pragma unroll
    for (int s = 0; s < 2; ++s) {
      bf16x8 fa[4], fb[4];
#pragma unroll
      for (int i = 0; i < 4; ++i) {
        int arow = wm + i * 16 + r;
        fa[i] = *(const bf16x8*)(As + arow * 64 + (((s * 4 + g) ^ (arow & 7)) << 3));
        int brow = wn + i * 16 + r;
        fb[i] = *(const bf16x8*)(Bs + brow * 64 + (((s * 4 + g) ^ (brow & 7)) << 3));
      }
#pragma unroll
      for (int i = 0; i < 4; ++i)
#pragma unroll
        for (int j = 0; j < 4; ++j)
          acc[i][j] = __builtin_amdgcn_mfma_f32_16x16x32_bf16(fa[i], fb[j], acc[i][j], 0, 0, 0);
    }
  }

#pragma unroll
  for (int i = 0; i < 4; ++i) {
#pragma unroll
    for (int j = 0; j < 4; ++j) {
      int col = n0 + wn + j * 16 + r;
      float b = bias[col];
      float sc = (MODE == 0 && col < qcols) ? qscale : 1.0f;
#pragma unroll
      for (int rr = 0; rr < 4; ++rr) {
        int row = m0 + wm + i * 16 + g * 4 + rr;
        float v = (acc[i][j][rr] + b) * sc;
        if (MODE == 0)
          ((bf16*)Cout)[(size_t)row * N + col] = (bf16)v;
        else
          ((float*)Cout)[(size_t)row * N + col] = v;
      }
    }
  }
}

// ================= fused flash attention, kv-split x2 in-block =================
// qkv: bf16 [4096][3072]; Q pre-scaled by 0.125*log2e. out: bf16 [4096][1024].
// Block: 4 waves = {2 q-tiles} x {2 kv-halves}. Grid 64x16 = 1024 blocks.
#define LDQ 3072

__global__ __launch_bounds__(256, 3) void attn_fwd3(const bf16* __restrict__ qkv,
                                                    bf16* __restrict__ out) {
  __shared__ __align__(16) bf16 Vt[2][2][64 * 64];  // [buf][half-tile][d*64+kv], chunk^= (d&7)
  __shared__ float ml[2][32][2];                    // [qt][q][m,l] from half-1 waves

  const int tid = threadIdx.x, lane = tid & 63, w = tid >> 6;
  const int hi = lane >> 5, q = lane & 31;
  const int qt = w & 1, half = w >> 1;
  const int h = blockIdx.y;
  const int q0 = blockIdx.x * 64 + qt * 32;
  const int kvbase = half * 2048;

  const bf16* Qg = qkv + h * 64;
  const bf16* Kg = qkv + 1024 + h * 64;
  const bf16* Vg = qkv + 2048 + h * 64;

  // Q B-frags: col=q, k = st*16 + hi*8 + j
  bf16x8 fq[4];
  {
    const bf16* qp = Qg + (size_t)(q0 + q) * LDQ + hi * 8;
#pragma unroll
    for (int st = 0; st < 4; ++st) fq[st] = *(const bf16x8*)(qp + st * 16);
  }

  // V staging: 128 threads per half-tile
  const int vtile = tid >> 7;
  const int t2 = tid & 127;
  const int kvp = t2 & 31, dgh = t2 >> 5;
  const int kv0 = kvp * 2;
  const int vkvbase = vtile * 2048;

  bf16x8 kpre[8];      // K rows (q, 32+q); single set, prefetch-overwrite (compiler-safe WAR)
  bf16x8 vreg[2][2];   // [dj][row 0/1]

  auto load_k = [&](int it) {
    const bf16* kp = Kg + (size_t)(kvbase + it * 64 + q) * LDQ + hi * 8;
#pragma unroll
    for (int st = 0; st < 4; ++st) {
      kpre[st]     = *(const bf16x8*)(kp + st * 16);
      kpre[4 + st] = *(const bf16x8*)(kp + (size_t)32 * LDQ + st * 16);
    }
  };
  auto load_v = [&](int it) {
    const bf16* vp = Vg + (size_t)(vkvbase + it * 64 + kv0) * LDQ;
#pragma unroll
    for (int dj = 0; dj < 2; ++dj) {
      int dg = dgh + dj * 4;
      vreg[dj][0] = *(const bf16x8*)(vp + dg * 8);
      vreg[dj][1] = *(const bf16x8*)(vp + LDQ + dg * 8);
    }
  };
  auto stage_v = [&](int buf) {
    bf16* base = &Vt[buf][vtile][0];
#pragma unroll
    for (int dj = 0; dj < 2; ++dj) {
      u16x8 lo = __builtin_bit_cast(u16x8, vreg[dj][0]);
      u16x8 hb = __builtin_bit_cast(u16x8, vreg[dj][1]);
#pragma unroll
      for (int jj = 0; jj < 8; ++jj) {
        int d = (dgh + dj * 4) * 8 + jj;
        u32 pk = (u32)lo[jj] | ((u32)hb[jj] << 16);
        *(u32*)(base + d * 64 + (((kvp >> 2) ^ (d & 7)) << 3) + (kv0 & 7)) = pk;
      }
    }
  };

  load_k(0);
  load_v(0);
  stage_v(0);

  f32x16 o0 = {}, o1 = {};
  float m_run = -1e30f, l_run = 0.f;
  __syncthreads();

  for (int it = 0; it < 32; ++it) {
    const int cur = it & 1, nxt = cur ^ 1;
    const int itn = (it + 1) & 31;   // wrap prefetch (last iter loads tile 0, unused)

    // ---- S^T = K * Q^T ----
    f32x16 p0 = {}, p1 = {};
    __builtin_amdgcn_s_setprio(1);
#pragma unroll
    for (int st = 0; st < 4; ++st) {
      p0 = __builtin_amdgcn_mfma_f32_32x32x16_bf16(kpre[st],     fq[st], p0, 0, 0, 0);
      p1 = __builtin_amdgcn_mfma_f32_32x32x16_bf16(kpre[4 + st], fq[st], p1, 0, 0, 0);
    }
    __builtin_amdgcn_s_setprio(0);

    // prefetch next K into same regs (consumed next iter)
    load_k(itn);

    // ---- in-register softmax (column q) ----
    float t16[16];
#pragma unroll
    for (int i = 0; i < 16; ++i) t16[i] = fmaxf(p0[i], p1[i]);
#pragma unroll
    for (int s2 = 8; s2 > 0; s2 >>= 1)
#pragma unroll
      for (int i = 0; i < s2; ++i) t16[i] = fmaxf(t16[i], t16[i + s2]);
    float mx = xhalf_max(t16[0]);

    if (__any(mx > m_run + 8.0f)) {     // defer-max (T13)
      float mnew = fmaxf(m_run, mx);
      float alpha = fast_exp2(m_run - mnew);
      l_run *= alpha;
#pragma unroll
      for (int i = 0; i < 16; ++i) { o0[i] *= alpha; o1[i] *= alpha; }
      m_run = mnew;
    }

#pragma unroll
    for (int i = 0; i < 16; ++i) p0[i] = fast_exp2(p0[i] - m_run);
#pragma unroll
    for (int i = 0; i < 16; ++i) p1[i] = fast_exp2(p1[i] - m_run);

    float s8[8];
#pragma unroll
    for (int i = 0; i < 8; ++i) s8[i] = (p0[i] + p0[i + 8]) + (p1[i] + p1[i + 8]);
#pragma unroll
    for (int s2 = 4; s2 > 0; s2 >>= 1)
#pragma unroll
      for (int i = 0; i < s2; ++i) s8[i] += s8[i + s2];
    l_run += xhalf_sum(s8[0]);

    // ---- P^T B-frags in-register (T12; distinct-value pl32swap only) ----
    u32x4 pb[4];
#pragma unroll
    for (int hf = 0; hf < 2; ++hf) {
#pragma unroll
      for (int qd = 0; qd < 2; ++qd) {
        int ks = hf * 2 + qd;
        u32 a0, b0, a1, b1;
        if (hf == 0) {
          a0 = cvtpk_bf16(p0[qd * 8 + 0], p0[qd * 8 + 1]);
          b0 = cvtpk_bf16(p0[qd * 8 + 4], p0[qd * 8 + 5]);
          a1 = cvtpk_bf16(p0[qd * 8 + 2], p0[qd * 8 + 3]);
          b1 = cvtpk_bf16(p0[qd * 8 + 6], p0[qd * 8 + 7]);
        } else {
          a0 = cvtpk_bf16(p1[qd * 8 + 0], p1[qd * 8 + 1]);
          b0 = cvtpk_bf16(p1[qd * 8 + 4], p1[qd * 8 + 5]);
          a1 = cvtpk_bf16(p1[qd * 8 + 2], p1[qd * 8 + 3]);
          b1 = cvtpk_bf16(p1[qd * 8 + 6], p1[qd * 8 + 7]);
        }
        pl32swap(a0, b0);
        pl32swap(a1, b1);
        pb[ks][0] = a0; pb[ks][1] = a1; pb[ks][2] = b0; pb[ks][3] = b1;
      }
    }

    // prefetch next V (covered by PV + ds_write wait)
    load_v(itn);

    // ---- O^T += V^T * P^T ----
    const bf16* vb = &Vt[cur][half][0];
    __builtin_amdgcn_s_setprio(1);
#pragma unroll
    for (int ks = 0; ks < 4; ++ks) {
      bf16x8 pf = __builtin_bit_cast(bf16x8, pb[ks]);
      int ck = ((2 * ks + hi) ^ (q & 7)) << 3;
      bf16x8 av0 = *(const bf16x8*)(vb + q * 64 + ck);
      bf16x8 av1 = *(const bf16x8*)(vb + (32 + q) * 64 + ck);
      o0 = __builtin_amdgcn_mfma_f32_32x32x16_bf16(av0, pf, o0, 0, 0, 0);
      o1 = __builtin_amdgcn_mfma_f32_32x32x16_bf16(av1, pf, o1, 0, 0, 0);
    }
    __builtin_amdgcn_s_setprio(0);

    // stage next V tiles into the other buffer
    stage_v(nxt);
    __syncthreads();
  }

  // ---- combine kv-halves through LDS, normalize, store ----
  float* comb = (float*)&Vt[0][0][0];
  if (half == 1) {
    float* dst = comb + qt * 2048 + lane * 32;
#pragma unroll
    for (int c = 0; c < 8; ++c) {
      f32x4 v;
      if (c < 4) { v[0] = o0[c*4+0]; v[1] = o0[c*4+1]; v[2] = o0[c*4+2]; v[3] = o0[c*4+3]; }
      else       { v[0] = o1[(c-4)*4+0]; v[1] = o1[(c-4)*4+1]; v[2] = o1[(c-4)*4+2]; v[3] = o1[(c-4)*4+3]; }
      *(f32x4*)(dst + c * 4) = v;
    }
    if (hi == 0) { ml[qt][q][0] = m_run; ml[qt][q][1] = l_run; }
  }
  __syncthreads();
  if (half == 0) {
    const float* src = comb + qt * 2048 + lane * 32;
    float mB = ml[qt][q][0], lB = ml[qt][q][1];
    float m = fmaxf(m_run, mB);
    float wA = fast_exp2(m_run - m), wB = fast_exp2(mB - m);
    float linv = 1.0f / (l_run * wA + lB * wB);
    wA *= linv; wB *= linv;
    bf16* op = out + (size_t)(q0 + q) * 1024 + h * 64;
#pragma unroll
    for (int c = 0; c < 8; ++c) {
      f32x4 ob = *(const f32x4*)(src + c * 4);
      float e0, e1, e2, e3;
      if (c < 4) { e0 = o0[c*4+0]; e1 = o0[c*4+1]; e2 = o0[c*4+2]; e3 = o0[c*4+3]; }
      else       { e0 = o1[(c-4)*4+0]; e1 = o1[(c-4)*4+1]; e2 = o1[(c-4)*4+2]; e3 = o1[(c-4)*4+3]; }
      e0 = e0 * wA + ob[0] * wB;
      e1 = e1 * wA + ob[1] * wB;
      e2 = e2 * wA + ob[2] * wB;
      e3 = e3 * wA + ob[3] * wB;
      int db = c >> 2, rg = c & 3;
      int dbase = db * 32 + rg * 8 + hi * 4;
      uint2 stv;
      stv.x = cvtpk_bf16(e0, e1);
      stv.y = cvtpk_bf16(e2, e3);
      *(uint2*)(op + dbase) = stv;
    }
  }
}

// ================= launcher =================
extern "C" void kernel_launch(void* const* d_in, const int* in_sizes, int n_in,
                              void* d_out, int out_size, void* d_ws, size_t ws_size,
                              hipStream_t stream) {
  const float* x     = (const float*)d_in[0];
  const float* w_qkv = (const float*)d_in[1];
  const float* b_qkv = (const float*)d_in[2];
  const float* w_out = (const float*)d_in[3];
  const float* b_out = (const float*)d_in[4];
  float* outp = (float*)d_out;

  char* ws = (char*)d_ws;
  bf16* qkv   = (bf16*)(ws);                          // [4096][3072]  24 MB
  bf16* xbf   = (bf16*)(ws + 24u * 1024 * 1024);      // [4096][1024]   8 MB (reused as attn_out)
  bf16* wqkvT = (bf16*)(ws + 32u * 1024 * 1024);      // [3072][1024]   6 MB
  bf16* woutT = (bf16*)(ws + 38u * 1024 * 1024);      // [1024][1024]   2 MB

  cvt_bf16_kernel<<<4096, 256, 0, stream>>>(x, xbf, 4096 * 1024);
  transpose_cvt_kernel<<<dim3(48, 16), 256, 0, stream>>>(w_qkv, wqkvT, 1024, 3072);
  transpose_cvt_kernel<<<dim3(16, 16), 256, 0, stream>>>(w_out, woutT, 1024, 1024);

  gemm_bt<0><<<dim3(32, 24), 256, 0, stream>>>(xbf, wqkvT, b_qkv, qkv,
                                               4096, 3072, 1024,
                                               0.125f * 1.44269504088896f, 1024);

  attn_fwd3<<<dim3(64, 16), 256, 0, stream>>>(qkv, xbf);

  gemm_bt<1><<<dim3(32, 8), 256, 0, stream>>>(xbf, woutT, b_out, outp,
                                              4096, 1024, 1024, 1.0f, 0);
}

// Round 5
// 182.559 us; speedup vs baseline: 1.5072x; 1.5072x over previous
//
#include <hip/hip_runtime.h>
#include <stdint.h>
#include <stddef.h>

typedef __bf16 bf16;
typedef uint32_t u32;
typedef __attribute__((ext_vector_type(8))) __bf16 bf16x8;
typedef __attribute__((ext_vector_type(4))) __bf16 bf16x4;
typedef __attribute__((ext_vector_type(4))) float f32x4;
typedef __attribute__((ext_vector_type(16))) float f32x16;
typedef __attribute__((ext_vector_type(8))) unsigned short u16x8;
typedef __attribute__((ext_vector_type(4))) u32 u32x4;

// -------- async global->LDS (16B) --------
__device__ __forceinline__ void gload_lds16(const void* g, void* l) {
  __builtin_amdgcn_global_load_lds(
      (const __attribute__((address_space(1))) unsigned int*)g,
      (__attribute__((address_space(3))) unsigned int*)l, 16, 0, 0);
}

__device__ __forceinline__ float fast_exp2(float x) {
#if __has_builtin(__builtin_amdgcn_exp2f)
  return __builtin_amdgcn_exp2f(x);
#else
  float r; asm("v_exp_f32 %0, %1" : "=v"(r) : "v"(x)); return r;
#endif
}

__device__ __forceinline__ u32 cvtpk_bf16(float lo, float hi_) {
  u32 r;
  asm("v_cvt_pk_bf16_f32 %0, %1, %2" : "=v"(r) : "v"(lo), "v"(hi_));
  return r;
}

// swap: a[32:63] <-> b[0:31]  (ONLY safe with distinct-origin a,b values)
__device__ __forceinline__ void pl32swap(u32& a, u32& b) {
  asm("v_permlane32_swap_b32 %0, %1" : "+v"(a), "+&v"(b));
}

// cross-half (lane ^ 32) reduce — DS shuffle (bulletproof)
__device__ __forceinline__ float xhalf_max(float v) {
  return fmaxf(v, __shfl_xor(v, 32, 64));
}
__device__ __forceinline__ float xhalf_sum(float v) {
  return v + __shfl_xor(v, 32, 64);
}

// ================= convert x: fp32 -> bf16 =================
__global__ void cvt_bf16_kernel(const float* __restrict__ in, bf16* __restrict__ out, int n) {
  int i = (blockIdx.x * blockDim.x + threadIdx.x) * 4;
  if (i < n) {
    float4 v = *(const float4*)(in + i);
    bf16x4 o;
    o[0] = (bf16)v.x; o[1] = (bf16)v.y; o[2] = (bf16)v.z; o[3] = (bf16)v.w;
    *(bf16x4*)(out + i) = o;
  }
}

// ======= transpose+convert: in[K_][N_] fp32 -> out[N_][K_] bf16 =======
__global__ void transpose_cvt_kernel(const float* __restrict__ in, bf16* __restrict__ out,
                                     int K_, int N_) {
  __shared__ __align__(16) bf16 t[64][65];
  const int nb = blockIdx.x * 64, kb = blockIdx.y * 64;
  const int c = threadIdx.x & 63, r0 = (threadIdx.x >> 6) * 16;
#pragma unroll
  for (int i = 0; i < 16; ++i) {
    int rr = r0 + i;
    t[c][rr] = (bf16)in[(size_t)(kb + rr) * N_ + nb + c];
  }
  __syncthreads();
#pragma unroll
  for (int i = 0; i < 16; ++i) {
    int rr = r0 + i;
    out[(size_t)(nb + rr) * K_ + kb + c] = t[rr][c];
  }
}

// ================= GEMM: C[M,N] = A[M,K] * BT[N,K]^T + bias =================
#define BM 128
#define BN 128
#define BK 64

template <int MODE>
__global__ __launch_bounds__(256) void gemm_bt(
    const bf16* __restrict__ A, const bf16* __restrict__ BT,
    const float* __restrict__ bias, void* __restrict__ Cout,
    int M, int N, int K, float qscale, int qcols) {
  __shared__ __align__(16) bf16 As[BM * BK];
  __shared__ __align__(16) bf16 Bs[BN * BK];
  const int tid = threadIdx.x;
  const int lane = tid & 63;
  const int w = tid >> 6;
  const int wm = (w >> 1) * 64;
  const int wn = (w & 1) * 64;
  const int m0 = blockIdx.x * BM;
  const int n0 = blockIdx.y * BN;
  const int r = lane & 15, g = lane >> 4;

  f32x4 acc[4][4] = {};

  for (int k0 = 0; k0 < K; k0 += BK) {
    __syncthreads();
#pragma unroll
    for (int i = 0; i < 4; ++i) {
      int id = tid + i * 256;
      int row = id >> 3, c = id & 7;
      int sc = c ^ (row & 7);
      gload_lds16(A + (size_t)(m0 + row) * K + k0 + sc * 8, As + id * 8);
      gload_lds16(BT + (size_t)(n0 + row) * K + k0 + sc * 8, Bs + id * 8);
    }
    __syncthreads();
#pragma unroll
    for (int s = 0; s < 2; ++s) {
      bf16x8 fa[4], fb[4];
#pragma unroll
      for (int i = 0; i < 4; ++i) {
        int arow = wm + i * 16 + r;
        fa[i] = *(const bf16x8*)(As + arow * 64 + (((s * 4 + g) ^ (arow & 7)) << 3));
        int brow = wn + i * 16 + r;
        fb[i] = *(const bf16x8*)(Bs + brow * 64 + (((s * 4 + g) ^ (brow & 7)) << 3));
      }
#pragma unroll
      for (int i = 0; i < 4; ++i)
#pragma unroll
        for (int j = 0; j < 4; ++j)
          acc[i][j] = __builtin_amdgcn_mfma_f32_16x16x32_bf16(fa[i], fb[j], acc[i][j], 0, 0, 0);
    }
  }

#pragma unroll
  for (int i = 0; i < 4; ++i) {
#pragma unroll
    for (int j = 0; j < 4; ++j) {
      int col = n0 + wn + j * 16 + r;
      float b = bias[col];
      float sc = (MODE == 0 && col < qcols) ? qscale : 1.0f;
#pragma unroll
      for (int rr = 0; rr < 4; ++rr) {
        int row = m0 + wm + i * 16 + g * 4 + rr;
        float v = (acc[i][j][rr] + b) * sc;
        if (MODE == 0)
          ((bf16*)Cout)[(size_t)row * N + col] = (bf16)v;
        else
          ((float*)Cout)[(size_t)row * N + col] = v;
      }
    }
  }
}

// ================= fused flash attention: 8 waves, kv-split x2, K in LDS ======
// qkv: bf16 [4096][3072]; Q pre-scaled by 0.125*log2e. out: bf16 [4096][1024].
// Block: 8 waves = {4 q-tiles x 32 rows} x {2 kv-halves}. Grid 32x16 = 512 = 2/CU.
#define LDQ 3072

__global__ __launch_bounds__(512, 4) void attn_fwd4(const bf16* __restrict__ qkv,
                                                    bf16* __restrict__ out) {
  __shared__ __align__(16) bf16 Kl[2][2][64 * 64];  // [buf][half][kv*64+d], chunk^=(kv&7)
  __shared__ __align__(16) bf16 Vt[2][2][64 * 64];  // [buf][half][d*64+kv], chunk^=(d&7)
  __shared__ float ml[4][32][2];                    // [qt][q][m,l] from half-1 waves

  const int tid = threadIdx.x, lane = tid & 63, w = tid >> 6;
  const int hi = lane >> 5, q = lane & 31;
  const int qt = w & 3, half = w >> 2;
  const int h = blockIdx.y;
  const int q0 = blockIdx.x * 128 + qt * 32;

  const bf16* Qg = qkv + h * 64;
  const bf16* Kg = qkv + 1024 + h * 64;
  const bf16* Vg = qkv + 2048 + h * 64;

  // Q B-frags: col=q, k = st*16 + hi*8 + j (loop-invariant)
  bf16x8 fq[4];
  {
    const bf16* qp = Qg + (size_t)(q0 + q) * LDQ + hi * 8;
#pragma unroll
    for (int st = 0; st < 4; ++st) fq[st] = *(const bf16x8*)(qp + st * 16);
  }

  // K staging: 512 threads x 2 chunks (one per half); linear dest, pre-swizzled src
  const int krow = tid >> 3, kc = tid & 7;
  const int ksc = kc ^ (krow & 7);
  // V staging: 256 threads per half; thread -> (kv pair, 8-wide d group)
  const int vhalf = tid >> 8;
  const int t2 = tid & 255;
  const int kvp = t2 & 31, dgh = t2 >> 5;
  const int kv0 = kvp * 2;

  bf16x8 vreg0, vreg1;

  auto issue_k = [&](int it, int buf) {
#pragma unroll
    for (int i = 0; i < 2; ++i)
      gload_lds16(Kg + (size_t)(i * 2048 + it * 64 + krow) * LDQ + ksc * 8,
                  &Kl[buf][i][tid * 8]);
  };
  auto load_v = [&](int it) {
    const bf16* vp = Vg + (size_t)(vhalf * 2048 + it * 64 + kv0) * LDQ + dgh * 8;
    vreg0 = *(const bf16x8*)vp;
    vreg1 = *(const bf16x8*)(vp + LDQ);
  };
  auto stage_v = [&](int buf) {
    bf16* base = &Vt[buf][vhalf][0];
    u16x8 lo = __builtin_bit_cast(u16x8, vreg0);
    u16x8 hb = __builtin_bit_cast(u16x8, vreg1);
#pragma unroll
    for (int jj = 0; jj < 8; ++jj) {
      int d = dgh * 8 + jj;
      u32 pk = (u32)lo[jj] | ((u32)hb[jj] << 16);
      *(u32*)(base + d * 64 + (((kvp >> 2) ^ (d & 7)) << 3) + (kv0 & 7)) = pk;
    }
  };

  issue_k(0, 0);
  load_v(0);
  stage_v(0);

  f32x16 o0 = {}, o1 = {};
  float m_run = -1e30f, l_run = 0.f;
  __syncthreads();

  for (int it = 0; it < 32; ++it) {
    const int cur = it & 1, nxt = cur ^ 1;
    const bool pf = (it < 31);

    // issue next-tile staging first (T14): full body hides the latency
    if (pf) { issue_k(it + 1, nxt); load_v(it + 1); }

    // ---- S^T = K * Q^T : D[kv][q], K A-frags from LDS ----
    const bf16* kb = &Kl[cur][half][0];
    f32x16 p0 = {}, p1 = {};
    __builtin_amdgcn_s_setprio(1);
#pragma unroll
    for (int st = 0; st < 4; ++st) {
      bf16x8 ka0 = *(const bf16x8*)(kb + q * 64 + (((2 * st + hi) ^ (q & 7)) << 3));
      bf16x8 ka1 = *(const bf16x8*)(kb + (32 + q) * 64 + (((2 * st + hi) ^ (q & 7)) << 3));
      p0 = __builtin_amdgcn_mfma_f32_32x32x16_bf16(ka0, fq[st], p0, 0, 0, 0);
      p1 = __builtin_amdgcn_mfma_f32_32x32x16_bf16(ka1, fq[st], p1, 0, 0, 0);
    }
    __builtin_amdgcn_s_setprio(0);

    // ---- in-register softmax (column q) ----
    float t16[16];
#pragma unroll
    for (int i = 0; i < 16; ++i) t16[i] = fmaxf(p0[i], p1[i]);
#pragma unroll
    for (int s2 = 8; s2 > 0; s2 >>= 1)
#pragma unroll
      for (int i = 0; i < s2; ++i) t16[i] = fmaxf(t16[i], t16[i + s2]);
    float mx = xhalf_max(t16[0]);

    if (__any(mx > m_run + 8.0f)) {     // defer-max (T13)
      float mnew = fmaxf(m_run, mx);
      float alpha = fast_exp2(m_run - mnew);
      l_run *= alpha;
#pragma unroll
      for (int i = 0; i < 16; ++i) { o0[i] *= alpha; o1[i] *= alpha; }
      m_run = mnew;
    }

#pragma unroll
    for (int i = 0; i < 16; ++i) p0[i] = fast_exp2(p0[i] - m_run);
#pragma unroll
    for (int i = 0; i < 16; ++i) p1[i] = fast_exp2(p1[i] - m_run);

    float s8[8];
#pragma unroll
    for (int i = 0; i < 8; ++i) s8[i] = (p0[i] + p0[i + 8]) + (p1[i] + p1[i + 8]);
#pragma unroll
    for (int s2 = 4; s2 > 0; s2 >>= 1)
#pragma unroll
      for (int i = 0; i < s2; ++i) s8[i] += s8[i + s2];
    l_run += xhalf_sum(s8[0]);

    // ---- P^T B-frags in-register (T12) ----
    u32x4 pb[4];
#pragma unroll
    for (int hf = 0; hf < 2; ++hf) {
#pragma unroll
      for (int qd = 0; qd < 2; ++qd) {
        int ks = hf * 2 + qd;
        u32 a0, b0, a1, b1;
        if (hf == 0) {
          a0 = cvtpk_bf16(p0[qd * 8 + 0], p0[qd * 8 + 1]);
          b0 = cvtpk_bf16(p0[qd * 8 + 4], p0[qd * 8 + 5]);
          a1 = cvtpk_bf16(p0[qd * 8 + 2], p0[qd * 8 + 3]);
          b1 = cvtpk_bf16(p0[qd * 8 + 6], p0[qd * 8 + 7]);
        } else {
          a0 = cvtpk_bf16(p1[qd * 8 + 0], p1[qd * 8 + 1]);
          b0 = cvtpk_bf16(p1[qd * 8 + 4], p1[qd * 8 + 5]);
          a1 = cvtpk_bf16(p1[qd * 8 + 2], p1[qd * 8 + 3]);
          b1 = cvtpk_bf16(p1[qd * 8 + 6], p1[qd * 8 + 7]);
        }
        pl32swap(a0, b0);
        pl32swap(a1, b1);
        pb[ks][0] = a0; pb[ks][1] = a1; pb[ks][2] = b0; pb[ks][3] = b1;
      }
    }

    // ---- O^T += V^T * P^T ----
    const bf16* vb = &Vt[cur][half][0];
    __builtin_amdgcn_s_setprio(1);
#pragma unroll
    for (int ks = 0; ks < 4; ++ks) {
      bf16x8 pf2 = __builtin_bit_cast(bf16x8, pb[ks]);
      int ck = ((2 * ks + hi) ^ (q & 7)) << 3;
      bf16x8 av0 = *(const bf16x8*)(vb + q * 64 + ck);
      bf16x8 av1 = *(const bf16x8*)(vb + (32 + q) * 64 + ck);
      o0 = __builtin_amdgcn_mfma_f32_32x32x16_bf16(av0, pf2, o0, 0, 0, 0);
      o1 = __builtin_amdgcn_mfma_f32_32x32x16_bf16(av1, pf2, o1, 0, 0, 0);
    }
    __builtin_amdgcn_s_setprio(0);

    // stage next V tile (waits on this iter's V global loads)
    if (pf) stage_v(nxt);
    __syncthreads();
  }

  // ---- combine kv-halves through LDS, normalize, store ----
  float* comb = (float*)&Kl[0][0][0];   // 32 KB, exactly Kl
  if (half == 1) {
    float* dst = comb + qt * 2048 + lane * 32;
#pragma unroll
    for (int c = 0; c < 8; ++c) {
      f32x4 v;
      if (c < 4) { v[0] = o0[c*4+0]; v[1] = o0[c*4+1]; v[2] = o0[c*4+2]; v[3] = o0[c*4+3]; }
      else       { v[0] = o1[(c-4)*4+0]; v[1] = o1[(c-4)*4+1]; v[2] = o1[(c-4)*4+2]; v[3] = o1[(c-4)*4+3]; }
      *(f32x4*)(dst + c * 4) = v;
    }
    if (hi == 0) { ml[qt][q][0] = m_run; ml[qt][q][1] = l_run; }
  }
  __syncthreads();
  if (half == 0) {
    const float* src = comb + qt * 2048 + lane * 32;
    float mB = ml[qt][q][0], lB = ml[qt][q][1];
    float m = fmaxf(m_run, mB);
    float wA = fast_exp2(m_run - m), wB = fast_exp2(mB - m);
    float linv = 1.0f / (l_run * wA + lB * wB);
    wA *= linv; wB *= linv;
    bf16* op = out + (size_t)(q0 + q) * 1024 + h * 64;
#pragma unroll
    for (int c = 0; c < 8; ++c) {
      f32x4 ob = *(const f32x4*)(src + c * 4);
      float e0, e1, e2, e3;
      if (c < 4) { e0 = o0[c*4+0]; e1 = o0[c*4+1]; e2 = o0[c*4+2]; e3 = o0[c*4+3]; }
      else       { e0 = o1[(c-4)*4+0]; e1 = o1[(c-4)*4+1]; e2 = o1[(c-4)*4+2]; e3 = o1[(c-4)*4+3]; }
      e0 = e0 * wA + ob[0] * wB;
      e1 = e1 * wA + ob[1] * wB;
      e2 = e2 * wA + ob[2] * wB;
      e3 = e3 * wA + ob[3] * wB;
      int db = c >> 2, rg = c & 3;
      int dbase = db * 32 + rg * 8 + hi * 4;
      uint2 stv;
      stv.x = cvtpk_bf16(e0, e1);
      stv.y = cvtpk_bf16(e2, e3);
      *(uint2*)(op + dbase) = stv;
    }
  }
}

// ================= launcher =================
extern "C" void kernel_launch(void* const* d_in, const int* in_sizes, int n_in,
                              void* d_out, int out_size, void* d_ws, size_t ws_size,
                              hipStream_t stream) {
  const float* x     = (const float*)d_in[0];
  const float* w_qkv = (const float*)d_in[1];
  const float* b_qkv = (const float*)d_in[2];
  const float* w_out = (const float*)d_in[3];
  const float* b_out = (const float*)d_in[4];
  float* outp = (float*)d_out;

  char* ws = (char*)d_ws;
  bf16* qkv   = (bf16*)(ws);                          // [4096][3072]  24 MB
  bf16* xbf   = (bf16*)(ws + 24u * 1024 * 1024);      // [4096][1024]   8 MB (reused as attn_out)
  bf16* wqkvT = (bf16*)(ws + 32u * 1024 * 1024);      // [3072][1024]   6 MB
  bf16* woutT = (bf16*)(ws + 38u * 1024 * 1024);      // [1024][1024]   2 MB

  cvt_bf16_kernel<<<4096, 256, 0, stream>>>(x, xbf, 4096 * 1024);
  transpose_cvt_kernel<<<dim3(48, 16), 256, 0, stream>>>(w_qkv, wqkvT, 1024, 3072);
  transpose_cvt_kernel<<<dim3(16, 16), 256, 0, stream>>>(w_out, woutT, 1024, 1024);

  gemm_bt<0><<<dim3(32, 24), 256, 0, stream>>>(xbf, wqkvT, b_qkv, qkv,
                                               4096, 3072, 1024,
                                               0.125f * 1.44269504088896f, 1024);

  attn_fwd4<<<dim3(32, 16), 512, 0, stream>>>(qkv, xbf);

  gemm_bt<1><<<dim3(32, 8), 256, 0, stream>>>(xbf, woutT, b_out, outp,
                                              4096, 1024, 1024, 1.0f, 0);
}

// Round 6
// 176.067 us; speedup vs baseline: 1.5628x; 1.0369x over previous
//
#include <hip/hip_runtime.h>
#include <stdint.h>
#include <stddef.h>

typedef __bf16 bf16;
typedef uint32_t u32;
typedef __attribute__((ext_vector_type(8))) __bf16 bf16x8;
typedef __attribute__((ext_vector_type(4))) __bf16 bf16x4;
typedef __attribute__((ext_vector_type(4))) float f32x4;
typedef __attribute__((ext_vector_type(16))) float f32x16;
typedef __attribute__((ext_vector_type(8))) unsigned short u16x8;
typedef __attribute__((ext_vector_type(4))) u32 u32x4;

// -------- async global->LDS (16B) --------
__device__ __forceinline__ void gload_lds16(const void* g, void* l) {
  __builtin_amdgcn_global_load_lds(
      (const __attribute__((address_space(1))) unsigned int*)g,
      (__attribute__((address_space(3))) unsigned int*)l, 16, 0, 0);
}

__device__ __forceinline__ float fast_exp2(float x) {
#if __has_builtin(__builtin_amdgcn_exp2f)
  return __builtin_amdgcn_exp2f(x);
#else
  float r; asm("v_exp_f32 %0, %1" : "=v"(r) : "v"(x)); return r;
#endif
}

__device__ __forceinline__ u32 cvtpk_bf16(float lo, float hi_) {
  u32 r;
  asm("v_cvt_pk_bf16_f32 %0, %1, %2" : "=v"(r) : "v"(lo), "v"(hi_));
  return r;
}

// swap: a[32:63] <-> b[0:31]  (ONLY safe with distinct-origin a,b values)
__device__ __forceinline__ void pl32swap(u32& a, u32& b) {
  asm("v_permlane32_swap_b32 %0, %1" : "+v"(a), "+&v"(b));
}

// cross-half (lane ^ 32) reduce — DS shuffle (bulletproof)
__device__ __forceinline__ float xhalf_max(float v) {
  return fmaxf(v, __shfl_xor(v, 32, 64));
}
__device__ __forceinline__ float xhalf_sum(float v) {
  return v + __shfl_xor(v, 32, 64);
}

__device__ __forceinline__ float max3f(float a, float b, float c) {
  return fmaxf(fmaxf(a, b), c);   // clang fuses to v_max3_f32
}

// ================= convert x: fp32 -> bf16 =================
__global__ void cvt_bf16_kernel(const float* __restrict__ in, bf16* __restrict__ out, int n) {
  int i = (blockIdx.x * blockDim.x + threadIdx.x) * 4;
  if (i < n) {
    float4 v = *(const float4*)(in + i);
    bf16x4 o;
    o[0] = (bf16)v.x; o[1] = (bf16)v.y; o[2] = (bf16)v.z; o[3] = (bf16)v.w;
    *(bf16x4*)(out + i) = o;
  }
}

// ======= transpose+convert: in[K_][N_] fp32 -> out[N_][K_] bf16 =======
__global__ void transpose_cvt_kernel(const float* __restrict__ in, bf16* __restrict__ out,
                                     int K_, int N_) {
  __shared__ __align__(16) bf16 t[64][65];
  const int nb = blockIdx.x * 64, kb = blockIdx.y * 64;
  const int c = threadIdx.x & 63, r0 = (threadIdx.x >> 6) * 16;
#pragma unroll
  for (int i = 0; i < 16; ++i) {
    int rr = r0 + i;
    t[c][rr] = (bf16)in[(size_t)(kb + rr) * N_ + nb + c];
  }
  __syncthreads();
#pragma unroll
  for (int i = 0; i < 16; ++i) {
    int rr = r0 + i;
    out[(size_t)(nb + rr) * K_ + kb + c] = t[rr][c];
  }
}

// ================= GEMM: C[M,N] = A[M,K] * BT[N,K]^T + bias =================
#define BM 128
#define BN 128
#define BK 64

template <int MODE>
__global__ __launch_bounds__(256) void gemm_bt(
    const bf16* __restrict__ A, const bf16* __restrict__ BT,
    const float* __restrict__ bias, void* __restrict__ Cout,
    int M, int N, int K, float qscale, int qcols) {
  __shared__ __align__(16) bf16 As[BM * BK];
  __shared__ __align__(16) bf16 Bs[BN * BK];
  const int tid = threadIdx.x;
  const int lane = tid & 63;
  const int w = tid >> 6;
  const int wm = (w >> 1) * 64;
  const int wn = (w & 1) * 64;
  const int m0 = blockIdx.x * BM;
  const int n0 = blockIdx.y * BN;
  const int r = lane & 15, g = lane >> 4;

  f32x4 acc[4][4] = {};

  for (int k0 = 0; k0 < K; k0 += BK) {
    __syncthreads();
#pragma unroll
    for (int i = 0; i < 4; ++i) {
      int id = tid + i * 256;
      int row = id >> 3, c = id & 7;
      int sc = c ^ (row & 7);
      gload_lds16(A + (size_t)(m0 + row) * K + k0 + sc * 8, As + id * 8);
      gload_lds16(BT + (size_t)(n0 + row) * K + k0 + sc * 8, Bs + id * 8);
    }
    __syncthreads();
#pragma unroll
    for (int s = 0; s < 2; ++s) {
      bf16x8 fa[4], fb[4];
#pragma unroll
      for (int i = 0; i < 4; ++i) {
        int arow = wm + i * 16 + r;
        fa[i] = *(const bf16x8*)(As + arow * 64 + (((s * 4 + g) ^ (arow & 7)) << 3));
        int brow = wn + i * 16 + r;
        fb[i] = *(const bf16x8*)(Bs + brow * 64 + (((s * 4 + g) ^ (brow & 7)) << 3));
      }
#pragma unroll
      for (int i = 0; i < 4; ++i)
#pragma unroll
        for (int j = 0; j < 4; ++j)
          acc[i][j] = __builtin_amdgcn_mfma_f32_16x16x32_bf16(fa[i], fb[j], acc[i][j], 0, 0, 0);
    }
  }

#pragma unroll
  for (int i = 0; i < 4; ++i) {
#pragma unroll
    for (int j = 0; j < 4; ++j) {
      int col = n0 + wn + j * 16 + r;
      float b = bias[col];
      float sc = (MODE == 0 && col < qcols) ? qscale : 1.0f;
#pragma unroll
      for (int rr = 0; rr < 4; ++rr) {
        int row = m0 + wm + i * 16 + g * 4 + rr;
        float v = (acc[i][j][rr] + b) * sc;
        if (MODE == 0)
          ((bf16*)Cout)[(size_t)row * N + col] = (bf16)v;
        else
          ((float*)Cout)[(size_t)row * N + col] = v;
      }
    }
  }
}

// ===== fused flash attention: 8 waves, kv-split x2, split-softmax interleave =====
// qkv: bf16 [4096][3072]; Q pre-scaled by 0.125*log2e. out: bf16 [4096][1024].
// Block: 8 waves = {4 q-tiles x 32 rows} x {2 kv-halves}. Grid 512 (1-D, XCD-chunked).
#define LDQ 3072
#define VSTR 68   // V^T LDS row stride (bf16 elems): 136B, odd multiple of 8B

__global__ __launch_bounds__(512, 4) void attn_fwd5(const bf16* __restrict__ qkv,
                                                    bf16* __restrict__ out) {
  __shared__ __align__(16) bf16 Kl[2][2][64 * 64];   // [buf][half][kv*64+d], chunk^=(kv&7)
  __shared__ __align__(16) bf16 Vt[2][2][64 * VSTR]; // [buf][half][d*VSTR+kv], padded stride
  __shared__ float ml[4][32][2];

  const int tid = threadIdx.x, lane = tid & 63, w = tid >> 6;
  const int hi = lane >> 5, q = lane & 31;
  const int qt = w & 3, half = w >> 2;

  // XCD-chunked swizzle: 512 blocks, 8 XCDs -> 64 consecutive per XCD (2 heads)
  const int bid = blockIdx.x;
  const int swz = (bid & 7) * 64 + (bid >> 3);
  const int h = swz >> 5, qb = swz & 31;
  const int q0 = qb * 128 + qt * 32;

  const bf16* Qg = qkv + h * 64;
  const bf16* Kg = qkv + 1024 + h * 64;
  const bf16* Vg = qkv + 2048 + h * 64;

  // Q B-frags: col=q, k = st*16 + hi*8 + j (loop-invariant)
  bf16x8 fq[4];
  {
    const bf16* qp = Qg + (size_t)(q0 + q) * LDQ + hi * 8;
#pragma unroll
    for (int st = 0; st < 4; ++st) fq[st] = *(const bf16x8*)(qp + st * 16);
  }

  // K staging: 512 threads x 2 chunks (one per half); linear dest, pre-swizzled src
  const int krow = tid >> 3, kc = tid & 7;
  const int ksc = kc ^ (krow & 7);
  // V staging: 256 threads per half
  const int vhalf = tid >> 8;
  const int t2 = tid & 255;
  const int kvp = t2 & 31, dgh = t2 >> 5;
  const int kv0 = kvp * 2;

  bf16x8 vreg0, vreg1;

  auto issue_k = [&](int it, int buf) {
#pragma unroll
    for (int i = 0; i < 2; ++i)
      gload_lds16(Kg + (size_t)(i * 2048 + it * 64 + krow) * LDQ + ksc * 8,
                  &Kl[buf][i][tid * 8]);
  };
  auto load_v = [&](int it) {
    const bf16* vp = Vg + (size_t)(vhalf * 2048 + it * 64 + kv0) * LDQ + dgh * 8;
    vreg0 = *(const bf16x8*)vp;
    vreg1 = *(const bf16x8*)(vp + LDQ);
  };
  auto stage_v = [&](int buf) {
    bf16* base = &Vt[buf][vhalf][0];
    u16x8 lo = __builtin_bit_cast(u16x8, vreg0);
    u16x8 hb = __builtin_bit_cast(u16x8, vreg1);
#pragma unroll
    for (int jj = 0; jj < 8; ++jj) {
      int d = dgh * 8 + jj;
      u32 pk = (u32)lo[jj] | ((u32)hb[jj] << 16);
      *(u32*)(base + d * VSTR + kv0) = pk;
    }
  };
  // V^T A-frag read: row d, kv slice ks*16 + hi*8 .. +7 (two b64, bank-spread)
  auto ldV = [&](const bf16* vb, int row, int ks) -> bf16x8 {
    const bf16* p = vb + row * VSTR + ks * 16 + hi * 8;
    bf16x4 lo = *(const bf16x4*)p;
    bf16x4 hb = *(const bf16x4*)(p + 4);
    return __builtin_shufflevector(lo, hb, 0, 1, 2, 3, 4, 5, 6, 7);
  };

  issue_k(0, 0);
  load_v(0);
  stage_v(0);

  f32x16 o0 = {}, o1 = {};
  float m_run = -1e30f, l_run = 0.f;
  __syncthreads();

  for (int it = 0; it < 32; ++it) {
    const int cur = it & 1, nxt = cur ^ 1;
    const bool pfch = (it < 31);

    // prefetch next tiles first: latency hides under full body (T14)
    if (pfch) { issue_k(it + 1, nxt); load_v(it + 1); }

    const bf16* kb = &Kl[cur][half][0];
    const bf16* vb = &Vt[cur][half][0];

    // ---- S^T = K * Q^T : p0 (kv 0..31) first, then p1 (kv 32..63) ----
    f32x16 p0 = {}, p1 = {};
    __builtin_amdgcn_s_setprio(1);
#pragma unroll
    for (int st = 0; st < 4; ++st) {
      bf16x8 ka0 = *(const bf16x8*)(kb + q * 64 + (((2 * st + hi) ^ (q & 7)) << 3));
      p0 = __builtin_amdgcn_mfma_f32_32x32x16_bf16(ka0, fq[st], p0, 0, 0, 0);
    }
#pragma unroll
    for (int st = 0; st < 4; ++st) {
      bf16x8 ka1 = *(const bf16x8*)(kb + (32 + q) * 64 + (((2 * st + hi) ^ (q & 7)) << 3));
      p1 = __builtin_amdgcn_mfma_f32_32x32x16_bf16(ka1, fq[st], p1, 0, 0, 0);
    }
    __builtin_amdgcn_s_setprio(0);

    // ================= softmax half A (p0) =================
    float a0 = max3f(p0[0], p0[1], p0[2]);
    float a1 = max3f(p0[3], p0[4], p0[5]);
    float a2 = max3f(p0[6], p0[7], p0[8]);
    float a3 = max3f(p0[9], p0[10], p0[11]);
    float a4 = max3f(p0[12], p0[13], p0[14]);
    float mxa = xhalf_max(max3f(max3f(a0, a1, a2), max3f(a3, a4, p0[15]), -1e30f));

    if (__any(mxa > m_run + 8.0f)) {     // defer-max (T13)
      float mnew = fmaxf(m_run, mxa);
      float alpha = fast_exp2(m_run - mnew);
      l_run *= alpha;
#pragma unroll
      for (int i = 0; i < 16; ++i) { o0[i] *= alpha; o1[i] *= alpha; }
      m_run = mnew;
    }
#pragma unroll
    for (int i = 0; i < 16; ++i) p0[i] = fast_exp2(p0[i] - m_run);

    float sa[8];
#pragma unroll
    for (int i = 0; i < 8; ++i) sa[i] = p0[i] + p0[i + 8];
#pragma unroll
    for (int s2 = 4; s2 > 0; s2 >>= 1)
#pragma unroll
      for (int i = 0; i < s2; ++i) sa[i] += sa[i + s2];
    float psum = sa[0];

    // cvt half A -> pb[0], pb[1]
    u32x4 pb[4];
#pragma unroll
    for (int qd = 0; qd < 2; ++qd) {
      u32 c0 = cvtpk_bf16(p0[qd * 8 + 0], p0[qd * 8 + 1]);
      u32 d0 = cvtpk_bf16(p0[qd * 8 + 4], p0[qd * 8 + 5]);
      u32 c1 = cvtpk_bf16(p0[qd * 8 + 2], p0[qd * 8 + 3]);
      u32 d1 = cvtpk_bf16(p0[qd * 8 + 6], p0[qd * 8 + 7]);
      pl32swap(c0, d0);
      pl32swap(c1, d1);
      pb[qd][0] = c0; pb[qd][1] = c1; pb[qd][2] = d0; pb[qd][3] = d1;
    }

    // ---- PV half A (kv 0..31): runs in MFMA pipe while half-B softmax issues ----
    __builtin_amdgcn_s_setprio(1);
#pragma unroll
    for (int ks = 0; ks < 2; ++ks) {
      bf16x8 pf2 = __builtin_bit_cast(bf16x8, pb[ks]);
      o0 = __builtin_amdgcn_mfma_f32_32x32x16_bf16(ldV(vb, q, ks), pf2, o0, 0, 0, 0);
      o1 = __builtin_amdgcn_mfma_f32_32x32x16_bf16(ldV(vb, 32 + q, ks), pf2, o1, 0, 0, 0);
    }
    __builtin_amdgcn_s_setprio(0);

    // ================= softmax half B (p1) =================
    float b0 = max3f(p1[0], p1[1], p1[2]);
    float b1 = max3f(p1[3], p1[4], p1[5]);
    float b2 = max3f(p1[6], p1[7], p1[8]);
    float b3 = max3f(p1[9], p1[10], p1[11]);
    float b4 = max3f(p1[12], p1[13], p1[14]);
    float mxb = xhalf_max(max3f(max3f(b0, b1, b2), max3f(b3, b4, p1[15]), -1e30f));

    if (__any(mxb > m_run + 8.0f)) {
      float mnew = fmaxf(m_run, mxb);
      float alpha = fast_exp2(m_run - mnew);
      l_run *= alpha;
      psum *= alpha;
#pragma unroll
      for (int i = 0; i < 16; ++i) { o0[i] *= alpha; o1[i] *= alpha; }
      m_run = mnew;
    }
#pragma unroll
    for (int i = 0; i < 16; ++i) p1[i] = fast_exp2(p1[i] - m_run);

    float sb[8];
#pragma unroll
    for (int i = 0; i < 8; ++i) sb[i] = p1[i] + p1[i + 8];
#pragma unroll
    for (int s2 = 4; s2 > 0; s2 >>= 1)
#pragma unroll
      for (int i = 0; i < s2; ++i) sb[i] += sb[i + s2];

    l_run += xhalf_sum(psum + sb[0]);

    // cvt half B -> pb[2], pb[3]
#pragma unroll
    for (int qd = 0; qd < 2; ++qd) {
      u32 c0 = cvtpk_bf16(p1[qd * 8 + 0], p1[qd * 8 + 1]);
      u32 d0 = cvtpk_bf16(p1[qd * 8 + 4], p1[qd * 8 + 5]);
      u32 c1 = cvtpk_bf16(p1[qd * 8 + 2], p1[qd * 8 + 3]);
      u32 d1 = cvtpk_bf16(p1[qd * 8 + 6], p1[qd * 8 + 7]);
      pl32swap(c0, d0);
      pl32swap(c1, d1);
      pb[2 + qd][0] = c0; pb[2 + qd][1] = c1; pb[2 + qd][2] = d0; pb[2 + qd][3] = d1;
    }

    // ---- PV half B (kv 32..63) ----
    __builtin_amdgcn_s_setprio(1);
#pragma unroll
    for (int ks = 2; ks < 4; ++ks) {
      bf16x8 pf2 = __builtin_bit_cast(bf16x8, pb[ks]);
      o0 = __builtin_amdgcn_mfma_f32_32x32x16_bf16(ldV(vb, q, ks), pf2, o0, 0, 0, 0);
      o1 = __builtin_amdgcn_mfma_f32_32x32x16_bf16(ldV(vb, 32 + q, ks), pf2, o1, 0, 0, 0);
    }
    __builtin_amdgcn_s_setprio(0);

    // stage next V tile (waits on this iter's V global loads)
    if (pfch) stage_v(nxt);
    __syncthreads();
  }

  // ---- combine kv-halves through LDS, normalize, store ----
  float* comb = (float*)&Kl[0][0][0];   // 32 KB
  if (half == 1) {
    float* dst = comb + qt * 2048 + lane * 32;
#pragma unroll
    for (int c = 0; c < 8; ++c) {
      f32x4 v;
      if (c < 4) { v[0] = o0[c*4+0]; v[1] = o0[c*4+1]; v[2] = o0[c*4+2]; v[3] = o0[c*4+3]; }
      else       { v[0] = o1[(c-4)*4+0]; v[1] = o1[(c-4)*4+1]; v[2] = o1[(c-4)*4+2]; v[3] = o1[(c-4)*4+3]; }
      *(f32x4*)(dst + c * 4) = v;
    }
    if (hi == 0) { ml[qt][q][0] = m_run; ml[qt][q][1] = l_run; }
  }
  __syncthreads();
  if (half == 0) {
    const float* src = comb + qt * 2048 + lane * 32;
    float mB = ml[qt][q][0], lB = ml[qt][q][1];
    float m = fmaxf(m_run, mB);
    float wA = fast_exp2(m_run - m), wB = fast_exp2(mB - m);
    float linv = 1.0f / (l_run * wA + lB * wB);
    wA *= linv; wB *= linv;
    bf16* op = out + (size_t)(q0 + q) * 1024 + h * 64;
#pragma unroll
    for (int c = 0; c < 8; ++c) {
      f32x4 ob = *(const f32x4*)(src + c * 4);
      float e0, e1, e2, e3;
      if (c < 4) { e0 = o0[c*4+0]; e1 = o0[c*4+1]; e2 = o0[c*4+2]; e3 = o0[c*4+3]; }
      else       { e0 = o1[(c-4)*4+0]; e1 = o1[(c-4)*4+1]; e2 = o1[(c-4)*4+2]; e3 = o1[(c-4)*4+3]; }
      e0 = e0 * wA + ob[0] * wB;
      e1 = e1 * wA + ob[1] * wB;
      e2 = e2 * wA + ob[2] * wB;
      e3 = e3 * wA + ob[3] * wB;
      int db = c >> 2, rg = c & 3;
      int dbase = db * 32 + rg * 8 + hi * 4;
      uint2 stv;
      stv.x = cvtpk_bf16(e0, e1);
      stv.y = cvtpk_bf16(e2, e3);
      *(uint2*)(op + dbase) = stv;
    }
  }
}

// ================= launcher =================
extern "C" void kernel_launch(void* const* d_in, const int* in_sizes, int n_in,
                              void* d_out, int out_size, void* d_ws, size_t ws_size,
                              hipStream_t stream) {
  const float* x     = (const float*)d_in[0];
  const float* w_qkv = (const float*)d_in[1];
  const float* b_qkv = (const float*)d_in[2];
  const float* w_out = (const float*)d_in[3];
  const float* b_out = (const float*)d_in[4];
  float* outp = (float*)d_out;

  char* ws = (char*)d_ws;
  bf16* qkv   = (bf16*)(ws);                          // [4096][3072]  24 MB
  bf16* xbf   = (bf16*)(ws + 24u * 1024 * 1024);      // [4096][1024]   8 MB (reused as attn_out)
  bf16* wqkvT = (bf16*)(ws + 32u * 1024 * 1024);      // [3072][1024]   6 MB
  bf16* woutT = (bf16*)(ws + 38u * 1024 * 1024);      // [1024][1024]   2 MB

  cvt_bf16_kernel<<<4096, 256, 0, stream>>>(x, xbf, 4096 * 1024);
  transpose_cvt_kernel<<<dim3(48, 16), 256, 0, stream>>>(w_qkv, wqkvT, 1024, 3072);
  transpose_cvt_kernel<<<dim3(16, 16), 256, 0, stream>>>(w_out, woutT, 1024, 1024);

  gemm_bt<0><<<dim3(32, 24), 256, 0, stream>>>(xbf, wqkvT, b_qkv, qkv,
                                               4096, 3072, 1024,
                                               0.125f * 1.44269504088896f, 1024);

  attn_fwd5<<<512, 512, 0, stream>>>(qkv, xbf);

  gemm_bt<1><<<dim3(32, 8), 256, 0, stream>>>(xbf, woutT, b_out, outp,
                                              4096, 1024, 1024, 1.0f, 0);
}